// Round 1
// baseline (16380.534 us; speedup 1.0000x reference)
//
#include <hip/hip_runtime.h>
#include <stdint.h>

#define SEQ  2048
#define HID  2048
#define INP  1024
#define OUTW 512

__device__ __forceinline__ unsigned short f2bf(float x){
  unsigned int u = __float_as_uint(x);
  u += 0x7fffu + ((u >> 16) & 1u);           // RNE
  return (unsigned short)(u >> 16);
}
__device__ __forceinline__ float bf_lo(unsigned int w){ return __uint_as_float(w << 16); }
__device__ __forceinline__ float bf_hi(unsigned int w){ return __uint_as_float(w & 0xffff0000u); }
__device__ __forceinline__ float sigmoid_f(float x){ return 1.0f/(1.0f + __expf(-x)); }
__device__ __forceinline__ float tanh_f(float x){
  x = fminf(15.0f, fmaxf(-15.0f, x));
  float e = __expf(-2.0f*x);
  return (1.0f - e)/(1.0f + e);
}

// ---------------- Phase A: Xproj[b][t][g*8+u] = W_g[j][2048:] @ x_t + b_g[j], bf16 ----------------
// A-rows: ar in [0,8192) = 4 gates stacked. Tile 64x64, BK=16, 256 thr, 4x4 micro.
__global__ __launch_bounds__(256)
void xproj_gemm(const float* __restrict__ Wf, const float* __restrict__ Wi,
                const float* __restrict__ Wc, const float* __restrict__ Wo,
                const float* __restrict__ bfv, const float* __restrict__ biv,
                const float* __restrict__ bcv, const float* __restrict__ bov,
                const float* __restrict__ X, unsigned short* __restrict__ xproj)
{
  __shared__ float As[16][68];
  __shared__ float Bs[16][68];
  const int t0 = blockIdx.x * 64;
  const int r0 = blockIdx.y * 64;
  const int gate = r0 >> 11;
  const int j0 = r0 & 2047;
  const float* Wg = gate==0?Wf:gate==1?Wi:gate==2?Wc:Wo;
  const float* bg = gate==0?bfv:gate==1?biv:gate==2?bcv:bov;
  const int tid = threadIdx.x;
  const int tx = tid & 15, ty = tid >> 4;
  const int lr = tid >> 2;
  const int lk = (tid & 3) * 4;
  float acc[4][4] = {};
  for (int k0 = 0; k0 < INP; k0 += 16){
    float4 av = *(const float4*)(Wg + (size_t)(j0+lr)*3072 + 2048 + k0 + lk);
    float4 bv = *(const float4*)(X  + (size_t)(t0+lr)*INP  + k0 + lk);
    __syncthreads();
    As[lk+0][lr]=av.x; As[lk+1][lr]=av.y; As[lk+2][lr]=av.z; As[lk+3][lr]=av.w;
    Bs[lk+0][lr]=bv.x; Bs[lk+1][lr]=bv.y; Bs[lk+2][lr]=bv.z; Bs[lk+3][lr]=bv.w;
    __syncthreads();
    #pragma unroll
    for (int kk=0;kk<16;kk++){
      float a[4], bb[4];
      #pragma unroll
      for (int i=0;i<4;i++) a[i]  = As[kk][ty*4+i];
      #pragma unroll
      for (int j=0;j<4;j++) bb[j] = Bs[kk][tx*4+j];
      #pragma unroll
      for (int i=0;i<4;i++)
        #pragma unroll
        for (int j=0;j<4;j++)
          acc[i][j] = fmaf(a[i], bb[j], acc[i][j]);
    }
  }
  #pragma unroll
  for (int i=0;i<4;i++){
    int j = j0 + ty*4 + i;
    float bias = bg[j];
    int bb = j >> 3, u = j & 7;
    #pragma unroll
    for (int jj=0;jj<4;jj++){
      int t = t0 + tx*4 + jj;
      size_t idx = ((size_t)bb*SEQ + t)*32 + gate*8 + u;
      xproj[idx] = f2bf(acc[i][jj] + bias);
    }
  }
}

// ---------------- Phase B: persistent recurrent scan ----------------
// 256 blocks (1/CU) x 256 thr. Block b owns hidden units [8b,8b+8); wave w = gate w.
// Weight slice (32 rows x 2048 cols) lives bf16-packed in 128 VGPRs/lane.
// Lane l covers cols {8l+512k + 0..7 : k=0..3}. h exchanged via agent-scope stores + grid barrier.
__global__ __launch_bounds__(256, 1)
void lstm_persistent(const float* __restrict__ Wf, const float* __restrict__ Wi,
                     const float* __restrict__ Wc, const float* __restrict__ Wo,
                     const unsigned short* __restrict__ xproj,
                     float* __restrict__ hist,          // d_out hidden region [SEQ][HID]
                     const float* __restrict__ zrow,    // 2048 zeros (h_{-1})
                     unsigned int* __restrict__ bar)    // [0]=global, [32*(1+x)]=per-group
{
  const int b    = blockIdx.x;
  const int tid  = threadIdx.x;
  const int wv   = tid >> 6;
  const int lane = tid & 63;

  __shared__ unsigned int h_lds[HID/2];  // packed bf16 pairs, word W = cols (2W,2W+1)
  __shared__ float g_lds[32];
  __shared__ float c_lds[8];
  __shared__ int dead;

  const float* Wg = (wv==0) ? Wf : (wv==1) ? Wi : (wv==2) ? Wc : Wo;

  unsigned int wreg[8][16];
  #pragma unroll
  for (int e=0;e<8;e++){
    const float* rowp = Wg + (size_t)(b*8+e)*3072;
    #pragma unroll
    for (int kc=0;kc<4;kc++){
      const float* p = rowp + 8*lane + 512*kc;
      float4 f0 = *(const float4*)(p);
      float4 f1 = *(const float4*)(p+4);
      wreg[e][kc*4+0] = (unsigned)f2bf(f0.x) | ((unsigned)f2bf(f0.y)<<16);
      wreg[e][kc*4+1] = (unsigned)f2bf(f0.z) | ((unsigned)f2bf(f0.w)<<16);
      wreg[e][kc*4+2] = (unsigned)f2bf(f1.x) | ((unsigned)f2bf(f1.y)<<16);
      wreg[e][kc*4+3] = (unsigned)f2bf(f1.z) | ((unsigned)f2bf(f1.w)<<16);
    }
  }
  if (tid < 8) c_lds[tid] = 0.0f;
  if (tid == 0) dead = 0;
  __syncthreads();

  for (int t=0; t<SEQ; t++){
    // stage h_{t-1} into LDS as packed bf16 (coalesced fp32 read, 8/thread)
    const float* hsrc = (t==0) ? zrow : (hist + (size_t)(t-1)*HID);
    float4 a0 = *(const float4*)(hsrc + tid*8);
    float4 a1 = *(const float4*)(hsrc + tid*8 + 4);
    uint4 pk;
    pk.x = (unsigned)f2bf(a0.x) | ((unsigned)f2bf(a0.y)<<16);
    pk.y = (unsigned)f2bf(a0.z) | ((unsigned)f2bf(a0.w)<<16);
    pk.z = (unsigned)f2bf(a1.x) | ((unsigned)f2bf(a1.y)<<16);
    pk.w = (unsigned)f2bf(a1.z) | ((unsigned)f2bf(a1.w)<<16);
    *(uint4*)&h_lds[tid*4] = pk;

    float xp = 0.0f;   // x-projection + bias, prefetched early
    if (lane < 8) xp = bf_lo((unsigned)xproj[((size_t)b*SEQ + t)*32 + wv*8 + lane]);
    __syncthreads();

    // 32 cols/lane dot against register-resident weights
    float acc[8] = {0,0,0,0,0,0,0,0};
    #pragma unroll
    for (int kc=0;kc<4;kc++){
      uint4 hw = *(const uint4*)&h_lds[4*lane + 256*kc];   // conflict-free b128
      unsigned int hwv[4] = {hw.x, hw.y, hw.z, hw.w};
      float hf[8];
      #pragma unroll
      for (int m=0;m<4;m++){ hf[2*m] = bf_lo(hwv[m]); hf[2*m+1] = bf_hi(hwv[m]); }
      #pragma unroll
      for (int e=0;e<8;e++){
        #pragma unroll
        for (int m=0;m<4;m++){
          unsigned int w = wreg[e][kc*4+m];
          acc[e] = fmaf(bf_lo(w), hf[2*m],   acc[e]);
          acc[e] = fmaf(bf_hi(w), hf[2*m+1], acc[e]);
        }
      }
    }

    // wave-wide reduce each of the 8 rows; lane e keeps row e
    float pre = 0.0f;
    #pragma unroll
    for (int e=0;e<8;e++){
      float v = acc[e];
      v += __shfl_xor(v, 32); v += __shfl_xor(v, 16); v += __shfl_xor(v, 8);
      v += __shfl_xor(v, 4);  v += __shfl_xor(v, 2);  v += __shfl_xor(v, 1);
      if (lane == e) pre = v;
    }
    if (lane < 8){
      float p = pre + xp;
      g_lds[wv*8 + lane] = (wv == 2) ? tanh_f(p) : sigmoid_f(p);
    }
    __syncthreads();

    if (tid < 8){
      float f  = g_lds[tid],    ii = g_lds[8+tid];
      float cc = g_lds[16+tid], o  = g_lds[24+tid];
      float c = fmaf(f, c_lds[tid], ii*cc);
      c_lds[tid] = c;
      float h = o * tanh_f(c);
      // write-through (agent scope) so other XCDs' L2 misses hit fresh LLC data
      __hip_atomic_store(hist + (size_t)t*HID + b*8 + tid, h,
                         __ATOMIC_RELAXED, __HIP_MEMORY_SCOPE_AGENT);
    }
    __syncthreads();

    // hierarchical grid barrier: 8 groups of 32 -> global counter; monotonic targets
    if (tid == 0 && !dead){
      __builtin_amdgcn_fence(__ATOMIC_RELEASE, "agent");
      unsigned int lt = 32u*(unsigned)(t+1);
      if (__hip_atomic_fetch_add(&bar[32*(1+(b&7))], 1u,
                                 __ATOMIC_RELAXED, __HIP_MEMORY_SCOPE_AGENT) == lt - 1u)
        __hip_atomic_fetch_add(&bar[0], 1u, __ATOMIC_RELAXED, __HIP_MEMORY_SCOPE_AGENT);
      unsigned int gt = 8u*(unsigned)(t+1);
      int guard = 0;
      while (__hip_atomic_load(&bar[0], __ATOMIC_RELAXED, __HIP_MEMORY_SCOPE_AGENT) < gt){
        __builtin_amdgcn_s_sleep(1);
        if (++guard > (1<<23)) { dead = 1; break; }   // fail wrong, never hang
      }
      __builtin_amdgcn_fence(__ATOMIC_ACQUIRE, "agent");
    }
    __syncthreads();
  }
}

// ---------------- Phase C: y[t][o] = W_y[o] @ h_t + b_y[o] ----------------
__global__ __launch_bounds__(256)
void ygemm(const float* __restrict__ hist, const float* __restrict__ Wy,
           const float* __restrict__ by, float* __restrict__ yout)
{
  __shared__ float As[16][68];
  __shared__ float Bs[16][68];
  const int o0 = blockIdx.x * 64;   // 8 tiles
  const int t0 = blockIdx.y * 64;   // 32 tiles
  const int tid = threadIdx.x;
  const int tx = tid & 15, ty = tid >> 4;
  const int lr = tid >> 2;
  const int lk = (tid & 3) * 4;
  float acc[4][4] = {};
  for (int k0 = 0; k0 < HID; k0 += 16){
    float4 av = *(const float4*)(hist + (size_t)(t0+lr)*HID + k0 + lk);
    float4 bv = *(const float4*)(Wy   + (size_t)(o0+lr)*HID + k0 + lk);
    __syncthreads();
    As[lk+0][lr]=av.x; As[lk+1][lr]=av.y; As[lk+2][lr]=av.z; As[lk+3][lr]=av.w;
    Bs[lk+0][lr]=bv.x; Bs[lk+1][lr]=bv.y; Bs[lk+2][lr]=bv.z; Bs[lk+3][lr]=bv.w;
    __syncthreads();
    #pragma unroll
    for (int kk=0;kk<16;kk++){
      float a[4], bb[4];
      #pragma unroll
      for (int i=0;i<4;i++) a[i]  = As[kk][ty*4+i];
      #pragma unroll
      for (int j=0;j<4;j++) bb[j] = Bs[kk][tx*4+j];
      #pragma unroll
      for (int i=0;i<4;i++)
        #pragma unroll
        for (int j=0;j<4;j++)
          acc[i][j] = fmaf(a[i], bb[j], acc[i][j]);
    }
  }
  #pragma unroll
  for (int i=0;i<4;i++){
    int t = t0 + ty*4 + i;
    #pragma unroll
    for (int jj=0;jj<4;jj++){
      int o = o0 + tx*4 + jj;
      yout[(size_t)t*OUTW + o] = acc[i][jj] + by[o];
    }
  }
}

extern "C" void kernel_launch(void* const* d_in, const int* in_sizes, int n_in,
                              void* d_out, int out_size, void* d_ws, size_t ws_size,
                              hipStream_t stream) {
  const float* X  = (const float*)d_in[0];
  const float* Wf = (const float*)d_in[1];
  const float* bf = (const float*)d_in[2];
  const float* Wi = (const float*)d_in[3];
  const float* bi = (const float*)d_in[4];
  const float* Wc = (const float*)d_in[5];
  const float* bc = (const float*)d_in[6];
  const float* Wo = (const float*)d_in[7];
  const float* bo = (const float*)d_in[8];
  const float* Wy = (const float*)d_in[9];
  const float* by = (const float*)d_in[10];

  float* yout = (float*)d_out;                       // [2048][512]
  float* hist = (float*)d_out + (size_t)SEQ*OUTW;    // [2048][2048]

  const size_t XPROJ_BYTES = (size_t)256*SEQ*32*sizeof(unsigned short); // 33,554,432
  const size_t BAR_OFF  = XPROJ_BYTES;
  const size_t ZROW_OFF = XPROJ_BYTES + 2048;
  const size_t NEEDED   = ZROW_OFF + HID*sizeof(float);
  if (ws_size < NEEDED) return;   // clean failure instead of corruption

  unsigned short* xproj = (unsigned short*)d_ws;
  unsigned int*   bar   = (unsigned int*)((char*)d_ws + BAR_OFF);
  float*          zrow  = (float*)((char*)d_ws + ZROW_OFF);

  // zero barrier counters + h_{-1} every call (ws is re-poisoned to 0xAA)
  hipMemsetAsync((char*)d_ws + BAR_OFF, 0, NEEDED - BAR_OFF, stream);

  dim3 gA(32, 128);
  xproj_gemm<<<gA, 256, 0, stream>>>(Wf,Wi,Wc,Wo, bf,bi,bc,bo, X, xproj);
  lstm_persistent<<<256, 256, 0, stream>>>(Wf,Wi,Wc,Wo, xproj, hist, zrow, bar);
  dim3 gY(8, 32);
  ygemm<<<gY, 256, 0, stream>>>(hist, Wy, by, yout);
}

// Round 2
// 6210.001 us; speedup vs baseline: 2.6378x; 2.6378x over previous
//
#include <hip/hip_runtime.h>
#include <stdint.h>

#define SEQ  2048
#define HID  2048
#define INP  1024
#define OUTW 512
#define SENT 0x7F7F7F7Fu   // 3.39e38f; |h|<1 so a real h word never matches

__device__ __forceinline__ unsigned short f2bf(float x){
  unsigned int u = __float_as_uint(x);
  u += 0x7fffu + ((u >> 16) & 1u);           // RNE
  return (unsigned short)(u >> 16);
}
__device__ __forceinline__ float bf_lo(unsigned int w){ return __uint_as_float(w << 16); }
__device__ __forceinline__ float bf_hi(unsigned int w){ return __uint_as_float(w & 0xffff0000u); }
__device__ __forceinline__ float sigmoid_f(float x){ return 1.0f/(1.0f + __expf(-x)); }
__device__ __forceinline__ float tanh_f(float x){
  x = fminf(15.0f, fmaxf(-15.0f, x));
  float e = __expf(-2.0f*x);
  return (1.0f - e)/(1.0f + e);
}

// ---------------- Phase 0: sentinel-fill hist + zero zrow ----------------
__global__ __launch_bounds__(256)
void fill_hist(uint4* __restrict__ hist4, float4* __restrict__ zrow4){
  size_t i = (size_t)blockIdx.x*blockDim.x + threadIdx.x;   // 1,048,576 uint4 = 16 MB
  hist4[i] = make_uint4(SENT,SENT,SENT,SENT);
  if (i < HID/4) zrow4[i] = make_float4(0.f,0.f,0.f,0.f);
}

// ---------------- Phase A: Xproj[b][t][g*8+u] = W_g[j][2048:] @ x_t + b_g[j], bf16 ----------------
__global__ __launch_bounds__(256)
void xproj_gemm(const float* __restrict__ Wf, const float* __restrict__ Wi,
                const float* __restrict__ Wc, const float* __restrict__ Wo,
                const float* __restrict__ bfv, const float* __restrict__ biv,
                const float* __restrict__ bcv, const float* __restrict__ bov,
                const float* __restrict__ X, unsigned short* __restrict__ xproj)
{
  __shared__ float As[16][68];
  __shared__ float Bs[16][68];
  const int t0 = blockIdx.x * 64;
  const int r0 = blockIdx.y * 64;
  const int gate = r0 >> 11;
  const int j0 = r0 & 2047;
  const float* Wg = gate==0?Wf:gate==1?Wi:gate==2?Wc:Wo;
  const float* bg = gate==0?bfv:gate==1?biv:gate==2?bcv:bov;
  const int tid = threadIdx.x;
  const int tx = tid & 15, ty = tid >> 4;
  const int lr = tid >> 2;
  const int lk = (tid & 3) * 4;
  float acc[4][4] = {};
  for (int k0 = 0; k0 < INP; k0 += 16){
    float4 av = *(const float4*)(Wg + (size_t)(j0+lr)*3072 + 2048 + k0 + lk);
    float4 bv = *(const float4*)(X  + (size_t)(t0+lr)*INP  + k0 + lk);
    __syncthreads();
    As[lk+0][lr]=av.x; As[lk+1][lr]=av.y; As[lk+2][lr]=av.z; As[lk+3][lr]=av.w;
    Bs[lk+0][lr]=bv.x; Bs[lk+1][lr]=bv.y; Bs[lk+2][lr]=bv.z; Bs[lk+3][lr]=bv.w;
    __syncthreads();
    #pragma unroll
    for (int kk=0;kk<16;kk++){
      float a[4], bb[4];
      #pragma unroll
      for (int i=0;i<4;i++) a[i]  = As[kk][ty*4+i];
      #pragma unroll
      for (int j=0;j<4;j++) bb[j] = Bs[kk][tx*4+j];
      #pragma unroll
      for (int i=0;i<4;i++)
        #pragma unroll
        for (int j=0;j<4;j++)
          acc[i][j] = fmaf(a[i], bb[j], acc[i][j]);
    }
  }
  #pragma unroll
  for (int i=0;i<4;i++){
    int j = j0 + ty*4 + i;
    float bias = bg[j];
    int bb = j >> 3, u = j & 7;
    #pragma unroll
    for (int jj=0;jj<4;jj++){
      int t = t0 + tx*4 + jj;
      size_t idx = ((size_t)bb*SEQ + t)*32 + gate*8 + u;
      xproj[idx] = f2bf(acc[i][jj] + bias);
    }
  }
}

// ---------------- Phase B: persistent recurrent scan, barrier-free ----------------
// 256 blocks x 512 thr (8 waves). Block b owns hidden units [8b,8b+8).
// Wave w: gate g=w&3, unit-half hh=w>>2 -> rows (hh*4..hh*4+3) of gate g, full 2048 cols.
// Weights fp32 in 128 VGPR/lane (no unpack). h exchange: sentinel-validated relaxed
// agent-scope loads/stores on hist — no grid barrier, no fences, no atomics-RMW.
__global__ __launch_bounds__(512, 2)
void lstm_persistent(const float* __restrict__ Wf, const float* __restrict__ Wi,
                     const float* __restrict__ Wc, const float* __restrict__ Wo,
                     const unsigned short* __restrict__ xproj,
                     float* __restrict__ hist,          // d_out hidden region [SEQ][HID]
                     const float* __restrict__ zrow)    // 2048 zeros (h_{-1})
{
  const int b    = blockIdx.x;
  const int tid  = threadIdx.x;
  const int wv   = tid >> 6;
  const int lane = tid & 63;
  const int g    = wv & 3;
  const int hh   = wv >> 2;

  __shared__ unsigned int h_lds[HID/2];  // packed bf16 pairs: word W = cols (2W,2W+1)
  __shared__ float g_lds[32];
  __shared__ float c_lds[8];

  const float* Wg = (g==0) ? Wf : (g==1) ? Wi : (g==2) ? Wc : Wo;

  // fp32 weights: wreg[r][kc*8+j] = W_g[b*8+hh*4+r][8*lane + 512*kc + j]
  float wreg[4][32];
  #pragma unroll
  for (int r=0;r<4;r++){
    const float* rowp = Wg + (size_t)(b*8 + hh*4 + r)*3072;
    #pragma unroll
    for (int kc=0;kc<4;kc++){
      float4 f0 = *(const float4*)(rowp + 8*lane + 512*kc);
      float4 f1 = *(const float4*)(rowp + 8*lane + 512*kc + 4);
      wreg[r][kc*8+0]=f0.x; wreg[r][kc*8+1]=f0.y; wreg[r][kc*8+2]=f0.z; wreg[r][kc*8+3]=f0.w;
      wreg[r][kc*8+4]=f1.x; wreg[r][kc*8+5]=f1.y; wreg[r][kc*8+6]=f1.z; wreg[r][kc*8+7]=f1.w;
    }
  }
  if (tid < 8) c_lds[tid] = 0.0f;   // read only by the same thread later

  const unsigned short* xpp = xproj + (size_t)b*SEQ*32 + g*8 + hh*4 + lane; // valid lane<4

  for (int t=0; t<SEQ; t++){
    // x-projection (tiny, cached) — issue before the h spin
    float xp = (lane < 4) ? bf_lo((unsigned)xpp[(size_t)t*32]) : 0.0f;

    // ---- acquire h_{t-1}: self-validating sentinel poll, LLC-scope loads ----
    const float* hsrc = (t==0) ? zrow : (hist + (size_t)(t-1)*HID);
    const unsigned long long* hp = (const unsigned long long*)hsrc + 2*tid;  // floats 4tid..4tid+3
    unsigned long long qa = __hip_atomic_load(hp,   __ATOMIC_RELAXED, __HIP_MEMORY_SCOPE_AGENT);
    unsigned long long qb = __hip_atomic_load(hp+1, __ATOMIC_RELAXED, __HIP_MEMORY_SCOPE_AGENT);
    int gd = 0;
    for(;;){
      bool ba = ((unsigned)qa==SENT) | ((unsigned)(qa>>32)==SENT);
      bool bb = ((unsigned)qb==SENT) | ((unsigned)(qb>>32)==SENT);
      if (!(ba|bb) || gd >= (1<<17)) break;   // guard: fail wrong, never hang
      if (ba) qa = __hip_atomic_load(hp,   __ATOMIC_RELAXED, __HIP_MEMORY_SCOPE_AGENT);
      if (bb) qb = __hip_atomic_load(hp+1, __ATOMIC_RELAXED, __HIP_MEMORY_SCOPE_AGENT);
      gd++;
    }
    unsigned a0=(unsigned)qa, a1=(unsigned)(qa>>32), a2=(unsigned)qb, a3=(unsigned)(qb>>32);
    uint2 pk;                                  // truncate-pack to bf16 pairs
    pk.x = (a1 & 0xffff0000u) | (a0 >> 16);
    pk.y = (a3 & 0xffff0000u) | (a2 >> 16);
    *(uint2*)&h_lds[2*tid] = pk;
    __syncthreads();

    // ---- dot: 4 rows x 32 cols/lane against register-resident fp32 weights ----
    float acc[4] = {0.f,0.f,0.f,0.f};
    #pragma unroll
    for (int kc=0;kc<4;kc++){
      uint4 hw = *(const uint4*)&h_lds[4*lane + 256*kc];   // cols 8*lane+512*kc+0..7
      float hf[8];
      hf[0]=bf_lo(hw.x); hf[1]=bf_hi(hw.x); hf[2]=bf_lo(hw.y); hf[3]=bf_hi(hw.y);
      hf[4]=bf_lo(hw.z); hf[5]=bf_hi(hw.z); hf[6]=bf_lo(hw.w); hf[7]=bf_hi(hw.w);
      #pragma unroll
      for (int r=0;r<4;r++)
        #pragma unroll
        for (int j=0;j<8;j++)
          acc[r] = fmaf(wreg[r][kc*8+j], hf[j], acc[r]);
    }

    // wave-wide reduce the 4 rows; lane r keeps row r
    float pre = 0.0f;
    #pragma unroll
    for (int r=0;r<4;r++){
      float v = acc[r];
      v += __shfl_xor(v, 32); v += __shfl_xor(v, 16); v += __shfl_xor(v, 8);
      v += __shfl_xor(v, 4);  v += __shfl_xor(v, 2);  v += __shfl_xor(v, 1);
      if (lane == r) pre = v;
    }
    if (lane < 4){
      float p = pre + xp;
      g_lds[g*8 + hh*4 + lane] = (g == 2) ? tanh_f(p) : sigmoid_f(p);
    }
    __syncthreads();

    // ---- cell update + publish h (fire-and-forget, self-validating) ----
    if (tid < 8){
      float f  = g_lds[tid],    ii = g_lds[8+tid];
      float cc = g_lds[16+tid], o  = g_lds[24+tid];
      float c = fmaf(f, c_lds[tid], ii*cc);
      c_lds[tid] = c;
      float h = o * tanh_f(c);
      __hip_atomic_store(hist + (size_t)t*HID + b*8 + tid, h,
                         __ATOMIC_RELAXED, __HIP_MEMORY_SCOPE_AGENT);
    }
    // no barrier: h_lds rewrite next iter is safe (all ds_reads drained at the
    // syncthreads above); g_lds reads here precede next iter's syncthreads.
  }
}

// ---------------- Phase C: y[t][o] = W_y[o] @ h_t + b_y[o] ----------------
__global__ __launch_bounds__(256)
void ygemm(const float* __restrict__ hist, const float* __restrict__ Wy,
           const float* __restrict__ by, float* __restrict__ yout)
{
  __shared__ float As[16][68];
  __shared__ float Bs[16][68];
  const int o0 = blockIdx.x * 64;
  const int t0 = blockIdx.y * 64;
  const int tid = threadIdx.x;
  const int tx = tid & 15, ty = tid >> 4;
  const int lr = tid >> 2;
  const int lk = (tid & 3) * 4;
  float acc[4][4] = {};
  for (int k0 = 0; k0 < HID; k0 += 16){
    float4 av = *(const float4*)(hist + (size_t)(t0+lr)*HID + k0 + lk);
    float4 bv = *(const float4*)(Wy   + (size_t)(o0+lr)*HID + k0 + lk);
    __syncthreads();
    As[lk+0][lr]=av.x; As[lk+1][lr]=av.y; As[lk+2][lr]=av.z; As[lk+3][lr]=av.w;
    Bs[lk+0][lr]=bv.x; Bs[lk+1][lr]=bv.y; Bs[lk+2][lr]=bv.z; Bs[lk+3][lr]=bv.w;
    __syncthreads();
    #pragma unroll
    for (int kk=0;kk<16;kk++){
      float a[4], bb[4];
      #pragma unroll
      for (int i=0;i<4;i++) a[i]  = As[kk][ty*4+i];
      #pragma unroll
      for (int j=0;j<4;j++) bb[j] = Bs[kk][tx*4+j];
      #pragma unroll
      for (int i=0;i<4;i++)
        #pragma unroll
        for (int j=0;j<4;j++)
          acc[i][j] = fmaf(a[i], bb[j], acc[i][j]);
    }
  }
  #pragma unroll
  for (int i=0;i<4;i++){
    int t = t0 + ty*4 + i;
    #pragma unroll
    for (int jj=0;jj<4;jj++){
      int o = o0 + tx*4 + jj;
      yout[(size_t)t*OUTW + o] = acc[i][jj] + by[o];
    }
  }
}

extern "C" void kernel_launch(void* const* d_in, const int* in_sizes, int n_in,
                              void* d_out, int out_size, void* d_ws, size_t ws_size,
                              hipStream_t stream) {
  const float* X  = (const float*)d_in[0];
  const float* Wf = (const float*)d_in[1];
  const float* bf = (const float*)d_in[2];
  const float* Wi = (const float*)d_in[3];
  const float* bi = (const float*)d_in[4];
  const float* Wc = (const float*)d_in[5];
  const float* bc = (const float*)d_in[6];
  const float* Wo = (const float*)d_in[7];
  const float* bo = (const float*)d_in[8];
  const float* Wy = (const float*)d_in[9];
  const float* by = (const float*)d_in[10];

  float* yout = (float*)d_out;                       // [2048][512]
  float* hist = (float*)d_out + (size_t)SEQ*OUTW;    // [2048][2048]

  const size_t XPROJ_BYTES = (size_t)256*SEQ*32*sizeof(unsigned short); // 33,554,432
  const size_t ZROW_OFF = (XPROJ_BYTES + 63) & ~(size_t)63;
  const size_t NEEDED   = ZROW_OFF + HID*sizeof(float);
  if (ws_size < NEEDED) return;   // clean failure instead of corruption

  unsigned short* xproj = (unsigned short*)d_ws;
  float*          zrow  = (float*)((char*)d_ws + ZROW_OFF);

  // sentinel-fill hist (16 MB) + zero h_{-1}; stream-ordered before the scan
  fill_hist<<<(SEQ*(size_t)HID/4)/256, 256, 0, stream>>>((uint4*)hist, (float4*)zrow);

  dim3 gA(32, 128);
  xproj_gemm<<<gA, 256, 0, stream>>>(Wf,Wi,Wc,Wo, bf,bi,bc,bo, X, xproj);
  lstm_persistent<<<256, 512, 0, stream>>>(Wf,Wi,Wc,Wo, xproj, hist, zrow);
  dim3 gY(8, 32);
  ygemm<<<gY, 256, 0, stream>>>(hist, Wy, by, yout);
}